// Round 3
// baseline (62.061 us; speedup 1.0000x reference)
//
#include <hip/hip_runtime.h>
#include <hip/hip_cooperative_groups.h>

namespace cg = cooperative_groups;

#define CLAMP_MIN 1e-12f
#define CLAMP_MAX 1e12f
#define BLOCKS 1024
#define WAVES_PER_BLOCK 4

// Single cooperative dispatch:
//   phase 1: one wave per sample computes ||x_i - c_{y_i}||^2 (== the
//            reference ||x||^2+||c||^2-2x.c in exact arithmetic), clamp,
//            4-wave block partial -> partials[blockIdx] in ws.
//   grid.sync()
//   phase 2: block 0 reduces the 1024 partials -> mean -> out[0].
// No atomics, no ws state that needs initialization -> deterministic and
// poison-safe across graph replays.
__global__ void __launch_bounds__(256) center_loss_coop_kernel(
    const float* __restrict__ x,
    const float* __restrict__ centers,
    const int* __restrict__ labels,
    float* __restrict__ out,
    float* __restrict__ partials,
    int batch, int feat) {
    cg::grid_group grid = cg::this_grid();

    const int wave = threadIdx.x >> 6;
    const int lane = threadIdx.x & 63;
    const int i = blockIdx.x * WAVES_PER_BLOCK + wave;  // sample index

    __shared__ float swave[WAVES_PER_BLOCK];

    float part = 0.0f;
    if (i < batch) {
        const float* xr = x + (size_t)i * feat;
        const float* cr = centers + (size_t)labels[i] * feat;
        // feat = 512: 2 iterations of float4 per lane.
        for (int k = lane * 4; k < feat; k += 64 * 4) {
            const float4 xv = *reinterpret_cast<const float4*>(xr + k);
            const float4 cv = *reinterpret_cast<const float4*>(cr + k);
            const float dx = xv.x - cv.x;
            const float dy = xv.y - cv.y;
            const float dz = xv.z - cv.z;
            const float dw = xv.w - cv.w;
            part += dx * dx + dy * dy + dz * dz + dw * dw;
        }
    }

    // Wave-64 shuffle reduction of the per-sample sum.
    #pragma unroll
    for (int off = 32; off > 0; off >>= 1) part += __shfl_down(part, off);

    if (lane == 0) {
        swave[wave] = (i < batch)
            ? fminf(fmaxf(part, CLAMP_MIN), CLAMP_MAX) : 0.0f;
    }
    __syncthreads();
    if (threadIdx.x == 0) {
        partials[blockIdx.x] = swave[0] + swave[1] + swave[2] + swave[3];
    }

    grid.sync();

    if (blockIdx.x == 0) {
        // 256 threads x float4 = exactly BLOCKS=1024 partials.
        const float4 pv = reinterpret_cast<const float4*>(partials)[threadIdx.x];
        float s = pv.x + pv.y + pv.z + pv.w;
        #pragma unroll
        for (int off = 32; off > 0; off >>= 1) s += __shfl_down(s, off);
        __shared__ float sfin[WAVES_PER_BLOCK];
        if (lane == 0) sfin[wave] = s;
        __syncthreads();
        if (threadIdx.x == 0) {
            out[0] = (sfin[0] + sfin[1] + sfin[2] + sfin[3]) / (float)batch;
        }
    }
}

extern "C" void kernel_launch(void* const* d_in, const int* in_sizes, int n_in,
                              void* d_out, int out_size, void* d_ws, size_t ws_size,
                              hipStream_t stream) {
    const float* x       = (const float*)d_in[0];
    const float* centers = (const float*)d_in[1];
    const int*   labels  = (const int*)d_in[2];
    float* out = (float*)d_out;

    int batch = in_sizes[2];             // 4096
    int feat  = in_sizes[0] / batch;     // 512

    float* partials = (float*)d_ws;      // BLOCKS floats, written before read

    void* args[] = {
        (void*)&x, (void*)&centers, (void*)&labels,
        (void*)&out, (void*)&partials, (void*)&batch, (void*)&feat
    };
    hipLaunchCooperativeKernel((const void*)center_loss_coop_kernel,
                               dim3(BLOCKS), dim3(256), args, 0, stream);
}

// Round 4
// 17.476 us; speedup vs baseline: 3.5513x; 3.5513x over previous
//
#include <hip/hip_runtime.h>

#define CLAMP_MIN 1e-12f
#define CLAMP_MAX 1e12f
#define NB 1024           // blocks; 4 waves/block, one sample per wave
#define MAGIC 0x5F3C0D1Eu

// Single dispatch, no init required:
//  - every block computes 4 per-sample distances (one wave each), clamps,
//    block-reduces -> partials[b] (agent-scope store), then release-stores
//    MAGIC to flags[b].
//  - block 0 spin-waits on all flags (acquire, agent scope), reduces the
//    1024 partials, writes mean to out[0].
// Idempotence makes this poison-safe across graph replays: flags are always
// set to the same MAGIC, partials to bit-identical values, so stale reads
// from a previous replay are harmless and nothing needs re-zeroing.
__global__ void __launch_bounds__(256) center_loss_onepass_kernel(
    const float* __restrict__ x,
    const float* __restrict__ centers,
    const int* __restrict__ labels,
    float* __restrict__ out,
    float* __restrict__ partials,
    unsigned int* __restrict__ flags,
    int batch, int feat) {
    const int wave = threadIdx.x >> 6;
    const int lane = threadIdx.x & 63;
    const int i = blockIdx.x * 4 + wave;   // sample index

    __shared__ float swave[4];

    float part = 0.0f;
    if (i < batch) {
        const float* xr = x + (size_t)i * feat;
        const float* cr = centers + (size_t)labels[i] * feat;
        // feat = 512: 2 iterations of one float4 per lane.
        for (int k = lane * 4; k < feat; k += 64 * 4) {
            const float4 xv = *reinterpret_cast<const float4*>(xr + k);
            const float4 cv = *reinterpret_cast<const float4*>(cr + k);
            const float dx = xv.x - cv.x;
            const float dy = xv.y - cv.y;
            const float dz = xv.z - cv.z;
            const float dw = xv.w - cv.w;
            part += dx * dx + dy * dy + dz * dz + dw * dw;
        }
    }

    #pragma unroll
    for (int off = 32; off > 0; off >>= 1) part += __shfl_down(part, off);

    if (lane == 0) {
        swave[wave] = (i < batch)
            ? fminf(fmaxf(part, CLAMP_MIN), CLAMP_MAX) : 0.0f;
    }
    __syncthreads();

    if (threadIdx.x == 0) {
        const float p = swave[0] + swave[1] + swave[2] + swave[3];
        __hip_atomic_store(&partials[blockIdx.x], p,
                           __ATOMIC_RELAXED, __HIP_MEMORY_SCOPE_AGENT);
        __hip_atomic_store(&flags[blockIdx.x], MAGIC,
                           __ATOMIC_RELEASE, __HIP_MEMORY_SCOPE_AGENT);
    }

    if (blockIdx.x != 0) return;

    // ---- block 0: wait for all blocks, then final reduce ----
    for (int f = threadIdx.x; f < NB; f += 256) {
        while (__hip_atomic_load(&flags[f], __ATOMIC_ACQUIRE,
                                 __HIP_MEMORY_SCOPE_AGENT) != MAGIC) {
            __builtin_amdgcn_s_sleep(1);
        }
    }
    __syncthreads();

    float s = 0.0f;
    for (int f = threadIdx.x; f < NB; f += 256) {
        s += __hip_atomic_load(&partials[f], __ATOMIC_RELAXED,
                               __HIP_MEMORY_SCOPE_AGENT);
    }
    #pragma unroll
    for (int off = 32; off > 0; off >>= 1) s += __shfl_down(s, off);

    __shared__ float sfin[4];
    if (lane == 0) sfin[wave] = s;
    __syncthreads();
    if (threadIdx.x == 0) {
        out[0] = (sfin[0] + sfin[1] + sfin[2] + sfin[3]) / (float)batch;
    }
}

extern "C" void kernel_launch(void* const* d_in, const int* in_sizes, int n_in,
                              void* d_out, int out_size, void* d_ws, size_t ws_size,
                              hipStream_t stream) {
    const float* x       = (const float*)d_in[0];
    const float* centers = (const float*)d_in[1];
    const int*   labels  = (const int*)d_in[2];
    float* out = (float*)d_out;

    const int batch = in_sizes[2];             // 4096
    const int feat  = in_sizes[0] / batch;     // 512

    float*        partials = (float*)d_ws;                       // NB floats
    unsigned int* flags    = (unsigned int*)((char*)d_ws + 8192); // NB uints

    center_loss_onepass_kernel<<<NB, 256, 0, stream>>>(
        x, centers, labels, out, partials, flags, batch, feat);
}

// Round 5
// 12.948 us; speedup vs baseline: 4.7930x; 1.3497x over previous
//
#include <hip/hip_runtime.h>

#define CLAMP_MIN 1e-12f
#define CLAMP_MAX 1e12f
#define NB 1024   // kernel-1 blocks; 4 waves/block, one sample per wave

// Kernel 1: one wave per sample -> clamped squared distance; 4 waves/block
// reduce to one partial per block.
__global__ void __launch_bounds__(256) center_dist_part_kernel(
    const float* __restrict__ x,
    const float* __restrict__ centers,
    const int* __restrict__ labels,
    float* __restrict__ partials,
    int batch, int feat) {
    const int wave = threadIdx.x >> 6;
    const int lane = threadIdx.x & 63;
    const int i = blockIdx.x * 4 + wave;   // sample index

    __shared__ float swave[4];

    float part = 0.0f;
    if (i < batch) {
        const float* xr = x + (size_t)i * feat;
        const float* cr = centers + (size_t)labels[i] * feat;
        if (feat == 512) {
            // Fully unrolled: issue all 4 loads, then the math (MLP).
            const int k0 = lane * 4;
            const float4 xv0 = *reinterpret_cast<const float4*>(xr + k0);
            const float4 cv0 = *reinterpret_cast<const float4*>(cr + k0);
            const float4 xv1 = *reinterpret_cast<const float4*>(xr + k0 + 256);
            const float4 cv1 = *reinterpret_cast<const float4*>(cr + k0 + 256);
            const float d0 = xv0.x - cv0.x, d1 = xv0.y - cv0.y;
            const float d2 = xv0.z - cv0.z, d3 = xv0.w - cv0.w;
            const float d4 = xv1.x - cv1.x, d5 = xv1.y - cv1.y;
            const float d6 = xv1.z - cv1.z, d7 = xv1.w - cv1.w;
            part = d0 * d0 + d1 * d1 + d2 * d2 + d3 * d3
                 + d4 * d4 + d5 * d5 + d6 * d6 + d7 * d7;
        } else {
            for (int k = lane * 4; k < feat; k += 64 * 4) {
                const float4 xv = *reinterpret_cast<const float4*>(xr + k);
                const float4 cv = *reinterpret_cast<const float4*>(cr + k);
                const float dx = xv.x - cv.x, dy = xv.y - cv.y;
                const float dz = xv.z - cv.z, dw = xv.w - cv.w;
                part += dx * dx + dy * dy + dz * dz + dw * dw;
            }
        }
    }

    // Wave-64 shuffle reduction of the per-sample sum.
    #pragma unroll
    for (int off = 32; off > 0; off >>= 1) part += __shfl_down(part, off);

    if (lane == 0) {
        swave[wave] = (i < batch)
            ? fminf(fmaxf(part, CLAMP_MIN), CLAMP_MAX) : 0.0f;
    }
    __syncthreads();
    if (threadIdx.x == 0) {
        partials[blockIdx.x] = swave[0] + swave[1] + swave[2] + swave[3];
    }
}

// Kernel 2: single wave reduces NB partials -> mean.
__global__ void __launch_bounds__(64) mean_kernel(
    const float* __restrict__ partials,
    float* __restrict__ out,
    int batch) {
    const int lane = threadIdx.x;
    const float4* p4 = reinterpret_cast<const float4*>(partials); // NB/4 vecs
    float s = 0.0f;
    #pragma unroll
    for (int k = lane; k < NB / 4; k += 64) {
        const float4 v = p4[k];
        s += v.x + v.y + v.z + v.w;
    }
    #pragma unroll
    for (int off = 32; off > 0; off >>= 1) s += __shfl_down(s, off);
    if (lane == 0) out[0] = s / (float)batch;
}

extern "C" void kernel_launch(void* const* d_in, const int* in_sizes, int n_in,
                              void* d_out, int out_size, void* d_ws, size_t ws_size,
                              hipStream_t stream) {
    const float* x       = (const float*)d_in[0];
    const float* centers = (const float*)d_in[1];
    const int*   labels  = (const int*)d_in[2];
    float* out = (float*)d_out;

    const int batch = in_sizes[2];             // 4096
    const int feat  = in_sizes[0] / batch;     // 512

    float* partials = (float*)d_ws;            // NB floats

    center_dist_part_kernel<<<NB, 256, 0, stream>>>(
        x, centers, labels, partials, batch, feat);
    mean_kernel<<<1, 64, 0, stream>>>(partials, out, batch);
}